// Round 11
// baseline (348.355 us; speedup 1.0000x reference)
//
#include <hip/hip_runtime.h>

#define N_NODES 100000
#define N_EDGES 1600000
#define F 128
#define BN_EPS 1e-5f
#define NB 391                        // node buckets of 256: ceil(100000/256)
#define NBP 392                       // padded
#define CAP 5120                      // per-bucket capacity in binned
#define EPB 4096                      // edges per bin_fill block
#define FILL_BLOCKS ((N_EDGES + EPB - 1) / EPB)   // 391
#define GATHER_BLOCKS 2048

// Workspace layout (bytes), all 64-aligned, NO overlaps (checked end-to-end):
//   [0, 1024)              stats: 256 floats (sum, sumsq)          } memset 0
//   [1024, 2588)           gcur:  NB ints (bucket cursors, init i*CAP)
//   [2624, 4192)           bbase: NB+1 ints
//   [4224, 404228)         offsets: N_NODES+1 ints
//   [404288, 6804288)      csr_src: N_EDGES ints
//   [6804352, 32404352)    hb:    N_NODES*128 bf16 (projected feats)
//   [32404416, 40412096)   binned: NB*CAP ints (8.0MB)
//   [32404416, 58004416)   aggb:  N_NODES*128 bf16  (ALIASES binned; binned
//                          is dead after csr_build, before gather writes)
#define O_STATS   0
#define O_GCUR    1024
#define O_BBASE   2624
#define O_OFF     4224
#define O_CSR     404288
#define O_HB      6804352
#define O_BINNED  32404416
#define O_AGGB    32404416

typedef __attribute__((ext_vector_type(8))) short bf16x8;
typedef __attribute__((ext_vector_type(4))) float f32x4;

__device__ __forceinline__ unsigned short f2bf(float f) {
    union { float f; unsigned u; } v; v.f = f;
    unsigned u = v.u;
    unsigned r = u + 0x7FFFu + ((u >> 16) & 1u);   // round-to-nearest-even
    return (unsigned short)(r >> 16);
}

__device__ __forceinline__ float4 bf4_to_f4(ushort4 u) {
    union { unsigned u; float f; } a, b, c, d;
    a.u = (unsigned)u.x << 16; b.u = (unsigned)u.y << 16;
    c.u = (unsigned)u.z << 16; d.u = (unsigned)u.w << 16;
    return make_float4(a.f, b.f, c.f, d.f);
}

// ---------------------------------------------------------------------------
// K0a: convert W to bf16
// ---------------------------------------------------------------------------
__global__ __launch_bounds__(256) void convert_w(
    const float* __restrict__ W, unsigned short* __restrict__ Wb)
{
    int i = blockIdx.x * blockDim.x + threadIdx.x;
    Wb[i] = f2bf(W[i]);
}

// ---------------------------------------------------------------------------
// K0b: init bucket cursors: gcur[i] = i*CAP
// ---------------------------------------------------------------------------
__global__ __launch_bounds__(256) void init_cur(int* __restrict__ gcur)
{
    int i = blockIdx.x * blockDim.x + threadIdx.x;
    if (i < NB) gcur[i] = i * CAP;
}

// ---------------------------------------------------------------------------
// K1: MFMA projection FIRST: hb = bf16( X @ Wb^T + b ).
// Reads fp32 X directly (converts in-reg -> no convert_x pass).
// Epilogue stages the 64x128 tile in LDS (stride 132) for coalesced bf16 out.
// ---------------------------------------------------------------------------
__global__ __launch_bounds__(256) void gemm_front(
    const float* __restrict__ X,             // [N,128] fp32
    const unsigned short* __restrict__ Wb,   // [128,128] bf16 [out][in]
    const float* __restrict__ bias,          // [128] fp32
    unsigned short* __restrict__ hb)         // [N,128] bf16
{
    __shared__ unsigned short hstage[64 * 132];   // 16.9 KB

    const int t   = threadIdx.x;
    const int w   = t >> 6;          // wave 0..3
    const int l   = t & 63;
    const int l16 = l & 15;
    const int lk  = l >> 4;          // 0..3
    const int row0    = blockIdx.x * 64;
    const int rowbase = row0 + w * 16;

    int arow   = rowbase + l16;
    int arow_c = (arow < N_NODES) ? arow : 0;

    f32x4 acc[8];
#pragma unroll
    for (int nt = 0; nt < 8; nt++) acc[nt] = (f32x4){0.f, 0.f, 0.f, 0.f};

    const float4* Xf4 = (const float4*)X;        // row = 32 float4
    const bf16x8* W8  = (const bf16x8*)Wb;

#pragma unroll
    for (int ks = 0; ks < 4; ks++) {
        float4 f0 = Xf4[(size_t)arow_c * 32 + (ks * 4 + lk) * 2 + 0];
        float4 f1 = Xf4[(size_t)arow_c * 32 + (ks * 4 + lk) * 2 + 1];
        union { short s[8]; bf16x8 v; } ua;
        ua.s[0] = (short)f2bf(f0.x); ua.s[1] = (short)f2bf(f0.y);
        ua.s[2] = (short)f2bf(f0.z); ua.s[3] = (short)f2bf(f0.w);
        ua.s[4] = (short)f2bf(f1.x); ua.s[5] = (short)f2bf(f1.y);
        ua.s[6] = (short)f2bf(f1.z); ua.s[7] = (short)f2bf(f1.w);
#pragma unroll
        for (int nt = 0; nt < 8; nt++) {
            int col = nt * 16 + l16;
            bf16x8 b = W8[(size_t)col * 16 + ks * 4 + lk];
            acc[nt] = __builtin_amdgcn_mfma_f32_16x16x32_bf16(ua.v, b, acc[nt], 0, 0, 0);
        }
    }

    // bias + stage to LDS (row-local = w*16 + lk*4 + r, stride 132)
    float bv[8];
#pragma unroll
    for (int nt = 0; nt < 8; nt++) bv[nt] = bias[nt * 16 + l16];
#pragma unroll
    for (int r = 0; r < 4; r++) {
        int rl = w * 16 + lk * 4 + r;
#pragma unroll
        for (int nt = 0; nt < 8; nt++)
            hstage[rl * 132 + nt * 16 + l16] = f2bf(acc[nt][r] + bv[nt]);
    }
    __syncthreads();

    // coalesced write-out: 64 rows x 16 chunks of ushort8
#pragma unroll
    for (int it = 0; it < 4; it++) {
        int idx   = t + it * 256;        // 0..1023
        int row   = idx >> 4;
        int chunk = idx & 15;
        int grow  = row0 + row;
        if (grow < N_NODES) {
            int4 v = *(const int4*)&hstage[row * 132 + chunk * 8];
            *(int4*)&hb[(size_t)grow * F + chunk * 8] = v;
        }
    }
}

// ---------------------------------------------------------------------------
// K2: multi-split bin fill (block-level write combining, 1 atomic/bucket/block)
// ---------------------------------------------------------------------------
__global__ __launch_bounds__(256) void bin_fill(
    const int* __restrict__ src,
    const int* __restrict__ dst,
    int* __restrict__ gcur,
    int* __restrict__ binned)
{
    __shared__ int hcnt[NBP];
    __shared__ int hloc[NBP];
    __shared__ int hbase[NB];
    __shared__ int ls[256];
    __shared__ int stage[EPB];
    __shared__ unsigned short sbkt[EPB];

    const int t  = threadIdx.x;
    const int eb = blockIdx.x * EPB;

    for (int i = t; i < NBP; i += 256) hcnt[i] = 0;
    __syncthreads();

    int v[16]; int bkt[16];
    unsigned valid = 0;
#pragma unroll
    for (int k = 0; k < 4; k++) {
        int base = eb + t * 4 + k * 1024;
        if (base + 3 < N_EDGES) {
            int4 s4 = *(const int4*)&src[base];
            int4 d4 = *(const int4*)&dst[base];
            bkt[k*4+0] = d4.x >> 8; v[k*4+0] = ((d4.x & 255) << 17) | s4.x;
            bkt[k*4+1] = d4.y >> 8; v[k*4+1] = ((d4.y & 255) << 17) | s4.y;
            bkt[k*4+2] = d4.z >> 8; v[k*4+2] = ((d4.z & 255) << 17) | s4.z;
            bkt[k*4+3] = d4.w >> 8; v[k*4+3] = ((d4.w & 255) << 17) | s4.w;
            valid |= 0xFu << (k * 4);
            atomicAdd(&hcnt[bkt[k*4+0]], 1);
            atomicAdd(&hcnt[bkt[k*4+1]], 1);
            atomicAdd(&hcnt[bkt[k*4+2]], 1);
            atomicAdd(&hcnt[bkt[k*4+3]], 1);
        } else {
#pragma unroll
            for (int j = 0; j < 4; j++) {
                int e = base + j;
                if (e < N_EDGES) {
                    int d = dst[e];
                    bkt[k*4+j] = d >> 8;
                    v[k*4+j]   = ((d & 255) << 17) | src[e];
                    valid |= 1u << (k * 4 + j);
                    atomicAdd(&hcnt[bkt[k*4+j]], 1);
                } else { bkt[k*4+j] = 0; v[k*4+j] = 0; }
            }
        }
    }
    __syncthreads();

    int a0 = (2 * t     < NBP) ? hcnt[2 * t]     : 0;
    int a1 = (2 * t + 1 < NBP) ? hcnt[2 * t + 1] : 0;
    ls[t] = a0 + a1;
    __syncthreads();
    for (int d = 1; d < 256; d <<= 1) {
        int u = (t >= d) ? ls[t - d] : 0;
        __syncthreads();
        ls[t] += u;
        __syncthreads();
    }
    int pb = ls[t] - (a0 + a1);
    if (2 * t     < NBP) hloc[2 * t]     = pb;
    if (2 * t + 1 < NBP) hloc[2 * t + 1] = pb + a0;
    __syncthreads();

    for (int i = t; i < NB; i += 256) {
        int c = hcnt[i];
        hbase[i] = c ? atomicAdd(&gcur[i], c) : 0;
    }
    __syncthreads();

    for (int i = t; i < NBP; i += 256) hcnt[i] = hloc[i];
    __syncthreads();

#pragma unroll
    for (int k = 0; k < 16; k++) {
        if (valid & (1u << k)) {
            int p = atomicAdd(&hcnt[bkt[k]], 1);
            stage[p] = v[k];
            sbkt[p]  = (unsigned short)bkt[k];
        }
    }
    __syncthreads();

    int m = min(EPB, N_EDGES - eb);
#pragma unroll
    for (int k = 0; k < 16; k++) {
        int p = t + k * 256;
        if (p < m) {
            int b = sbkt[p];
            binned[hbase[b] + (p - hloc[b])] = stage[p];
        }
    }
}

// ---------------------------------------------------------------------------
// K3: single block: bucket counts from final cursors -> dense csr bases
// ---------------------------------------------------------------------------
__global__ __launch_bounds__(512) void bucket_scan(
    const int* __restrict__ gcur,
    int* __restrict__ bbase)
{
    const int t = threadIdx.x;
    __shared__ int ls[512];
    int c = (t < NB) ? (gcur[t] - t * CAP) : 0;
    ls[t] = c;
    __syncthreads();
    for (int d = 1; d < 512; d <<= 1) {
        int u = (t >= d) ? ls[t - d] : 0;
        __syncthreads();
        ls[t] += u;
        __syncthreads();
    }
    if (t < NB) bbase[t] = ls[t] - c;
    if (t == NB - 1) bbase[NB] = ls[t];   // = N_EDGES
}

// ---------------------------------------------------------------------------
// K4: per-bucket CSR build (no deg output needed anymore)
// ---------------------------------------------------------------------------
__global__ __launch_bounds__(256) void csr_build(
    const int* __restrict__ binned,
    const int* __restrict__ gcur,
    const int* __restrict__ bbase,
    int* __restrict__ offsets,
    int* __restrict__ csr_src)
{
    const int b    = blockIdx.x;
    const int t    = threadIdx.x;
    const int rbeg = b * CAP;
    const int rend = gcur[b];
    const int nb0  = b * 256;

    __shared__ int cnt[256];
    __shared__ int ls[256];
    __shared__ int cur[256];
    cnt[t] = 0;
    __syncthreads();

    for (int i = rbeg + t; i < rend; i += 256)
        atomicAdd(&cnt[binned[i] >> 17], 1);
    __syncthreads();

    int v = cnt[t];
    ls[t] = v;
    __syncthreads();
    for (int d = 1; d < 256; d <<= 1) {
        int u = (t >= d) ? ls[t - d] : 0;
        __syncthreads();
        ls[t] += u;
        __syncthreads();
    }
    int ex = bbase[b] + ls[t] - v;
    cur[t] = ex;
    int node = nb0 + t;
    if (node < N_NODES) offsets[node] = ex;
    if (b == NB - 1 && t == 0) offsets[N_NODES] = N_EDGES;
    __syncthreads();

    for (int i = rbeg + t; i < rend; i += 256) {
        int w   = binned[i];
        int pos = atomicAdd(&cur[w >> 17], 1);
        csr_src[pos] = w & 0x1FFFF;
    }
}

// ---------------------------------------------------------------------------
// K5: pull-gather over PROJECTED feats + fused BN stats.
// aggb[v] = bf16( hb[v] + sum hb[src] ) ; stats += per-feature sum/sumsq.
// Grid-strided (2048 blocks) so stats atomics stay at 524K; per-lane column
// ownership (c0 = lane*4) is iteration-invariant -> register stat accum.
// ---------------------------------------------------------------------------
__global__ __launch_bounds__(256) void gather_kernel(
    const unsigned short* __restrict__ hb,
    const int* __restrict__ offsets,
    const int* __restrict__ csr_src,
    unsigned short* __restrict__ aggb,
    float* __restrict__ stats)
{
    const int t    = threadIdx.x;
    const int slot = t >> 5;
    const int lane = t & 31;

    float sums[4] = {0.f, 0.f, 0.f, 0.f};
    float ssqs[4] = {0.f, 0.f, 0.f, 0.f};

    const ushort4* X4 = (const ushort4*)hb;

    for (int g = blockIdx.x * 8 + slot; g < N_NODES; g += GATHER_BLOCKS * 8) {
        float4 acc = bf4_to_f4(X4[(size_t)g * 32 + lane]);   // self loop

        int beg = offsets[g];
        int end = offsets[g + 1];

        int e = beg;
        for (; e + 7 < end; e += 8) {
            ushort4 u0 = X4[(size_t)csr_src[e]     * 32 + lane];
            ushort4 u1 = X4[(size_t)csr_src[e + 1] * 32 + lane];
            ushort4 u2 = X4[(size_t)csr_src[e + 2] * 32 + lane];
            ushort4 u3 = X4[(size_t)csr_src[e + 3] * 32 + lane];
            ushort4 u4 = X4[(size_t)csr_src[e + 4] * 32 + lane];
            ushort4 u5 = X4[(size_t)csr_src[e + 5] * 32 + lane];
            ushort4 u6 = X4[(size_t)csr_src[e + 6] * 32 + lane];
            ushort4 u7 = X4[(size_t)csr_src[e + 7] * 32 + lane];
            float4 v0 = bf4_to_f4(u0), v1 = bf4_to_f4(u1);
            float4 v2 = bf4_to_f4(u2), v3 = bf4_to_f4(u3);
            float4 v4 = bf4_to_f4(u4), v5 = bf4_to_f4(u5);
            float4 v6 = bf4_to_f4(u6), v7 = bf4_to_f4(u7);
            acc.x += v0.x + v1.x + v2.x + v3.x + v4.x + v5.x + v6.x + v7.x;
            acc.y += v0.y + v1.y + v2.y + v3.y + v4.y + v5.y + v6.y + v7.y;
            acc.z += v0.z + v1.z + v2.z + v3.z + v4.z + v5.z + v6.z + v7.z;
            acc.w += v0.w + v1.w + v2.w + v3.w + v4.w + v5.w + v6.w + v7.w;
        }
        if (e + 3 < end) {
            ushort4 u0 = X4[(size_t)csr_src[e]     * 32 + lane];
            ushort4 u1 = X4[(size_t)csr_src[e + 1] * 32 + lane];
            ushort4 u2 = X4[(size_t)csr_src[e + 2] * 32 + lane];
            ushort4 u3 = X4[(size_t)csr_src[e + 3] * 32 + lane];
            float4 v0 = bf4_to_f4(u0), v1 = bf4_to_f4(u1);
            float4 v2 = bf4_to_f4(u2), v3 = bf4_to_f4(u3);
            acc.x += v0.x + v1.x + v2.x + v3.x;
            acc.y += v0.y + v1.y + v2.y + v3.y;
            acc.z += v0.z + v1.z + v2.z + v3.z;
            acc.w += v0.w + v1.w + v2.w + v3.w;
            e += 4;
        }
        for (; e < end; ++e) {
            float4 v0 = bf4_to_f4(X4[(size_t)csr_src[e] * 32 + lane]);
            acc.x += v0.x; acc.y += v0.y; acc.z += v0.z; acc.w += v0.w;
        }

        ushort4 o;
        o.x = f2bf(acc.x); o.y = f2bf(acc.y); o.z = f2bf(acc.z); o.w = f2bf(acc.w);
        ((ushort4*)aggb)[(size_t)g * 32 + lane] = o;

        sums[0] += acc.x; sums[1] += acc.y; sums[2] += acc.z; sums[3] += acc.w;
        ssqs[0] += acc.x * acc.x; ssqs[1] += acc.y * acc.y;
        ssqs[2] += acc.z * acc.z; ssqs[3] += acc.w * acc.w;
    }

    // block-level stats reduction (8 slots -> 1), one atomic per feature
    __shared__ float red[256 * 8];
    float* my = &red[t * 8];
    my[0] = sums[0]; my[1] = sums[1]; my[2] = sums[2]; my[3] = sums[3];
    my[4] = ssqs[0]; my[5] = ssqs[1]; my[6] = ssqs[2]; my[7] = ssqs[3];
    __syncthreads();

    if (t < 32) {
        float a8[8];
#pragma unroll
        for (int j = 0; j < 8; j++) a8[j] = red[t * 8 + j];
        for (int gg = 1; gg < 8; gg++)
#pragma unroll
            for (int j = 0; j < 8; j++) a8[j] += red[(gg * 32 + t) * 8 + j];
        int c0 = t * 4;
#pragma unroll
        for (int j = 0; j < 4; j++) {
            unsafeAtomicAdd(&stats[c0 + j],       a8[j]);
            unsafeAtomicAdd(&stats[128 + c0 + j], a8[4 + j]);
        }
    }
}

// ---------------------------------------------------------------------------
// K6: out = relu(gamma*(agg-mean)*rsqrt(var+eps)+beta) + node_feats
// agg read as bf16 (aggb), out written fp32 to d_out.
// ---------------------------------------------------------------------------
__global__ __launch_bounds__(256) void finalize_kernel(
    const float* __restrict__ stats,
    const float* __restrict__ gamma,
    const float* __restrict__ beta,
    const float* __restrict__ x,
    const unsigned short* __restrict__ aggb,
    float* __restrict__ out)
{
    __shared__ float s_scale[128];
    __shared__ float s_shift[128];
    const int t = threadIdx.x;
    if (t < 128) {
        const float inv_n = 1.0f / (float)N_NODES;
        float mean = stats[t] * inv_n;
        float var  = stats[128 + t] * inv_n - mean * mean;
        float sc   = gamma[t] * rsqrtf(var + BN_EPS);
        s_scale[t] = sc;
        s_shift[t] = beta[t] - mean * sc;
    }
    __syncthreads();

    const long long total = (long long)N_NODES * F / 4;
    long long i0 = (long long)blockIdx.x * blockDim.x + t;
    for (long long i = i0; i < total; i += (long long)gridDim.x * blockDim.x) {
        int cb = (int)(i & 31) * 4;
        float4 v  = bf4_to_f4(((const ushort4*)aggb)[i]);
        float4 xf = ((const float4*)x)[i];
        float4 o;
        o.x = fmaxf(v.x * s_scale[cb + 0] + s_shift[cb + 0], 0.f) + xf.x;
        o.y = fmaxf(v.y * s_scale[cb + 1] + s_shift[cb + 1], 0.f) + xf.y;
        o.z = fmaxf(v.z * s_scale[cb + 2] + s_shift[cb + 2], 0.f) + xf.z;
        o.w = fmaxf(v.w * s_scale[cb + 3] + s_shift[cb + 3], 0.f) + xf.w;
        ((float4*)out)[i] = o;
    }
}

// ---------------------------------------------------------------------------
extern "C" void kernel_launch(void* const* d_in, const int* in_sizes, int n_in,
                              void* d_out, int out_size, void* d_ws, size_t ws_size,
                              hipStream_t stream) {
    const float* node_feats = (const float*)d_in[0];
    const float* W          = (const float*)d_in[1];
    const float* b          = (const float*)d_in[2];
    const float* gamma      = (const float*)d_in[3];
    const float* beta       = (const float*)d_in[4];
    const int*   src        = (const int*)d_in[5];
    const int*   dst        = (const int*)d_in[6];

    float* out     = (float*)d_out;
    char*  ws      = (char*)d_ws;
    float* stats   = (float*)(ws + O_STATS);
    int*   gcur    = (int*)(ws + O_GCUR);
    int*   bbase   = (int*)(ws + O_BBASE);
    int*   offsets = (int*)(ws + O_OFF);
    int*   csr_src = (int*)(ws + O_CSR);
    unsigned short* hb   = (unsigned short*)(ws + O_HB);
    unsigned short* Wb   = (unsigned short*)(ws + O_HB);  // placeholder, fixed below
    unsigned short* aggb = (unsigned short*)(ws + O_AGGB);
    int*   binned  = (int*)(ws + O_BINNED);

    // Wb lives in the last 32KB of the stats..offsets gap? No — give it its
    // own spot right after bbase scan area, before offsets (4192..4224 is too
    // small). Use tail of aggb region? Simplest: place Wb after aggb end.
    Wb = (unsigned short*)(ws + 58004416);   // 32 KB, ends 58037184

    // zero stats
    hipMemsetAsync(d_ws, 0, 1024, stream);

    convert_w<<<64, 256, 0, stream>>>(W, Wb);
    init_cur<<<2, 256, 0, stream>>>(gcur);

    // projection first (independent of CSR build)
    gemm_front<<<(N_NODES + 63) / 64, 256, 0, stream>>>(node_feats, Wb, b, hb);

    bin_fill<<<FILL_BLOCKS, 256, 0, stream>>>(src, dst, gcur, binned);
    bucket_scan<<<1, 512, 0, stream>>>(gcur, bbase);
    csr_build<<<NB, 256, 0, stream>>>(binned, gcur, bbase, offsets, csr_src);

    // aggregate projected feats + fused BN stats
    gather_kernel<<<GATHER_BLOCKS, 256, 0, stream>>>(hb, offsets, csr_src, aggb, stats);

    finalize_kernel<<<2048, 256, 0, stream>>>(stats, gamma, beta, node_feats, aggb, out);
}

// Round 12
// 171.586 us; speedup vs baseline: 2.0302x; 2.0302x over previous
//
#include <hip/hip_runtime.h>

#define N_NODES 100000
#define N_EDGES 1600000
#define F 128
#define BN_EPS 1e-5f
#define NB 391                        // node buckets of 256
#define NBP 392
#define CAP 5120                      // per-bucket capacity in binned
#define EPB 4096                      // edges per bin_fill block
#define FILL_BLOCKS ((N_EDGES + EPB - 1) / EPB)   // 391
#define SP_BLOCKS 2048                // stats_partial blocks

// Workspace layout (bytes), all 64-aligned:
//   [0, 1024)              stats: 256 floats (sum, sumsq)          } memset 0
//   [1024, 2588)           gcur:  NB ints (bucket cursors, init i*CAP)
//   [2624, 4192)           bbase: NB+1 ints
//   [4224, 404228)         offsets: N_NODES+1 ints
//   [404288, 6804288)      csr_src: N_EDGES ints
//                          partial (2048*256 f32 = 2MB) ALIASES csr_src
//                          (csr dead after gather; partial written after)
//   [6804352, 32404352)    hb:    N_NODES*128 bf16 (projected feats)
//   [32404416, 40412096)   binned: NB*CAP ints (8.0MB)
//   [32404416, 58004416)   aggb:  N_NODES*128 bf16 (ALIASES binned; binned
//                          dead after csr_build, before gather writes)
//   [58004416, 58037184)   Wb: 128*128 bf16
#define O_STATS   0
#define O_GCUR    1024
#define O_BBASE   2624
#define O_OFF     4224
#define O_CSR     404288
#define O_PART    404288
#define O_HB      6804352
#define O_BINNED  32404416
#define O_AGGB    32404416
#define O_WB      58004416

typedef __attribute__((ext_vector_type(8))) short bf16x8;
typedef __attribute__((ext_vector_type(4))) float f32x4;

__device__ __forceinline__ unsigned short f2bf(float f) {
    union { float f; unsigned u; } v; v.f = f;
    unsigned u = v.u;
    unsigned r = u + 0x7FFFu + ((u >> 16) & 1u);   // round-to-nearest-even
    return (unsigned short)(r >> 16);
}

__device__ __forceinline__ float4 bf4_to_f4(ushort4 u) {
    union { unsigned u; float f; } a, b, c, d;
    a.u = (unsigned)u.x << 16; b.u = (unsigned)u.y << 16;
    c.u = (unsigned)u.z << 16; d.u = (unsigned)u.w << 16;
    return make_float4(a.f, b.f, c.f, d.f);
}

// ---------------------------------------------------------------------------
// K0a: convert W to bf16
// ---------------------------------------------------------------------------
__global__ __launch_bounds__(256) void convert_w(
    const float* __restrict__ W, unsigned short* __restrict__ Wb)
{
    int i = blockIdx.x * blockDim.x + threadIdx.x;
    Wb[i] = f2bf(W[i]);
}

// ---------------------------------------------------------------------------
// K0b: init bucket cursors
// ---------------------------------------------------------------------------
__global__ __launch_bounds__(256) void init_cur(int* __restrict__ gcur)
{
    int i = blockIdx.x * blockDim.x + threadIdx.x;
    if (i < NB) gcur[i] = i * CAP;
}

// ---------------------------------------------------------------------------
// K1: MFMA projection FIRST: hb = bf16( X @ Wb^T + b ). Reads fp32 X directly.
// ---------------------------------------------------------------------------
__global__ __launch_bounds__(256) void gemm_front(
    const float* __restrict__ X,
    const unsigned short* __restrict__ Wb,
    const float* __restrict__ bias,
    unsigned short* __restrict__ hb)
{
    __shared__ unsigned short hstage[64 * 132];

    const int t   = threadIdx.x;
    const int w   = t >> 6;
    const int l   = t & 63;
    const int l16 = l & 15;
    const int lk  = l >> 4;
    const int row0    = blockIdx.x * 64;
    const int rowbase = row0 + w * 16;

    int arow   = rowbase + l16;
    int arow_c = (arow < N_NODES) ? arow : 0;

    f32x4 acc[8];
#pragma unroll
    for (int nt = 0; nt < 8; nt++) acc[nt] = (f32x4){0.f, 0.f, 0.f, 0.f};

    const float4* Xf4 = (const float4*)X;
    const bf16x8* W8  = (const bf16x8*)Wb;

#pragma unroll
    for (int ks = 0; ks < 4; ks++) {
        float4 f0 = Xf4[(size_t)arow_c * 32 + (ks * 4 + lk) * 2 + 0];
        float4 f1 = Xf4[(size_t)arow_c * 32 + (ks * 4 + lk) * 2 + 1];
        union { short s[8]; bf16x8 v; } ua;
        ua.s[0] = (short)f2bf(f0.x); ua.s[1] = (short)f2bf(f0.y);
        ua.s[2] = (short)f2bf(f0.z); ua.s[3] = (short)f2bf(f0.w);
        ua.s[4] = (short)f2bf(f1.x); ua.s[5] = (short)f2bf(f1.y);
        ua.s[6] = (short)f2bf(f1.z); ua.s[7] = (short)f2bf(f1.w);
#pragma unroll
        for (int nt = 0; nt < 8; nt++) {
            int col = nt * 16 + l16;
            bf16x8 b = W8[(size_t)col * 16 + ks * 4 + lk];
            acc[nt] = __builtin_amdgcn_mfma_f32_16x16x32_bf16(ua.v, b, acc[nt], 0, 0, 0);
        }
    }

    float bv[8];
#pragma unroll
    for (int nt = 0; nt < 8; nt++) bv[nt] = bias[nt * 16 + l16];
#pragma unroll
    for (int r = 0; r < 4; r++) {
        int rl = w * 16 + lk * 4 + r;
#pragma unroll
        for (int nt = 0; nt < 8; nt++)
            hstage[rl * 132 + nt * 16 + l16] = f2bf(acc[nt][r] + bv[nt]);
    }
    __syncthreads();

#pragma unroll
    for (int it = 0; it < 4; it++) {
        int idx   = t + it * 256;
        int row   = idx >> 4;
        int chunk = idx & 15;
        int grow  = row0 + row;
        if (grow < N_NODES) {
            int4 v = *(const int4*)&hstage[row * 132 + chunk * 8];
            *(int4*)&hb[(size_t)grow * F + chunk * 8] = v;
        }
    }
}

// ---------------------------------------------------------------------------
// K2: multi-split bin fill (block-level write combining)
// ---------------------------------------------------------------------------
__global__ __launch_bounds__(256) void bin_fill(
    const int* __restrict__ src,
    const int* __restrict__ dst,
    int* __restrict__ gcur,
    int* __restrict__ binned)
{
    __shared__ int hcnt[NBP];
    __shared__ int hloc[NBP];
    __shared__ int hbase[NB];
    __shared__ int ls[256];
    __shared__ int stage[EPB];
    __shared__ unsigned short sbkt[EPB];

    const int t  = threadIdx.x;
    const int eb = blockIdx.x * EPB;

    for (int i = t; i < NBP; i += 256) hcnt[i] = 0;
    __syncthreads();

    int v[16]; int bkt[16];
    unsigned valid = 0;
#pragma unroll
    for (int k = 0; k < 4; k++) {
        int base = eb + t * 4 + k * 1024;
        if (base + 3 < N_EDGES) {
            int4 s4 = *(const int4*)&src[base];
            int4 d4 = *(const int4*)&dst[base];
            bkt[k*4+0] = d4.x >> 8; v[k*4+0] = ((d4.x & 255) << 17) | s4.x;
            bkt[k*4+1] = d4.y >> 8; v[k*4+1] = ((d4.y & 255) << 17) | s4.y;
            bkt[k*4+2] = d4.z >> 8; v[k*4+2] = ((d4.z & 255) << 17) | s4.z;
            bkt[k*4+3] = d4.w >> 8; v[k*4+3] = ((d4.w & 255) << 17) | s4.w;
            valid |= 0xFu << (k * 4);
            atomicAdd(&hcnt[bkt[k*4+0]], 1);
            atomicAdd(&hcnt[bkt[k*4+1]], 1);
            atomicAdd(&hcnt[bkt[k*4+2]], 1);
            atomicAdd(&hcnt[bkt[k*4+3]], 1);
        } else {
#pragma unroll
            for (int j = 0; j < 4; j++) {
                int e = base + j;
                if (e < N_EDGES) {
                    int d = dst[e];
                    bkt[k*4+j] = d >> 8;
                    v[k*4+j]   = ((d & 255) << 17) | src[e];
                    valid |= 1u << (k * 4 + j);
                    atomicAdd(&hcnt[bkt[k*4+j]], 1);
                } else { bkt[k*4+j] = 0; v[k*4+j] = 0; }
            }
        }
    }
    __syncthreads();

    int a0 = (2 * t     < NBP) ? hcnt[2 * t]     : 0;
    int a1 = (2 * t + 1 < NBP) ? hcnt[2 * t + 1] : 0;
    ls[t] = a0 + a1;
    __syncthreads();
    for (int d = 1; d < 256; d <<= 1) {
        int u = (t >= d) ? ls[t - d] : 0;
        __syncthreads();
        ls[t] += u;
        __syncthreads();
    }
    int pb = ls[t] - (a0 + a1);
    if (2 * t     < NBP) hloc[2 * t]     = pb;
    if (2 * t + 1 < NBP) hloc[2 * t + 1] = pb + a0;
    __syncthreads();

    for (int i = t; i < NB; i += 256) {
        int c = hcnt[i];
        hbase[i] = c ? atomicAdd(&gcur[i], c) : 0;
    }
    __syncthreads();

    for (int i = t; i < NBP; i += 256) hcnt[i] = hloc[i];
    __syncthreads();

#pragma unroll
    for (int k = 0; k < 16; k++) {
        if (valid & (1u << k)) {
            int p = atomicAdd(&hcnt[bkt[k]], 1);
            stage[p] = v[k];
            sbkt[p]  = (unsigned short)bkt[k];
        }
    }
    __syncthreads();

    int m = min(EPB, N_EDGES - eb);
#pragma unroll
    for (int k = 0; k < 16; k++) {
        int p = t + k * 256;
        if (p < m) {
            int b = sbkt[p];
            binned[hbase[b] + (p - hloc[b])] = stage[p];
        }
    }
}

// ---------------------------------------------------------------------------
// K3: bucket counts from cursors -> dense csr bases
// ---------------------------------------------------------------------------
__global__ __launch_bounds__(512) void bucket_scan(
    const int* __restrict__ gcur,
    int* __restrict__ bbase)
{
    const int t = threadIdx.x;
    __shared__ int ls[512];
    int c = (t < NB) ? (gcur[t] - t * CAP) : 0;
    ls[t] = c;
    __syncthreads();
    for (int d = 1; d < 512; d <<= 1) {
        int u = (t >= d) ? ls[t - d] : 0;
        __syncthreads();
        ls[t] += u;
        __syncthreads();
    }
    if (t < NB) bbase[t] = ls[t] - c;
    if (t == NB - 1) bbase[NB] = ls[t];
}

// ---------------------------------------------------------------------------
// K4: per-bucket CSR build
// ---------------------------------------------------------------------------
__global__ __launch_bounds__(256) void csr_build(
    const int* __restrict__ binned,
    const int* __restrict__ gcur,
    const int* __restrict__ bbase,
    int* __restrict__ offsets,
    int* __restrict__ csr_src)
{
    const int b    = blockIdx.x;
    const int t    = threadIdx.x;
    const int rbeg = b * CAP;
    const int rend = gcur[b];
    const int nb0  = b * 256;

    __shared__ int cnt[256];
    __shared__ int ls[256];
    __shared__ int cur[256];
    cnt[t] = 0;
    __syncthreads();

    for (int i = rbeg + t; i < rend; i += 256)
        atomicAdd(&cnt[binned[i] >> 17], 1);
    __syncthreads();

    int v = cnt[t];
    ls[t] = v;
    __syncthreads();
    for (int d = 1; d < 256; d <<= 1) {
        int u = (t >= d) ? ls[t - d] : 0;
        __syncthreads();
        ls[t] += u;
        __syncthreads();
    }
    int ex = bbase[b] + ls[t] - v;
    cur[t] = ex;
    int node = nb0 + t;
    if (node < N_NODES) offsets[node] = ex;
    if (b == NB - 1 && t == 0) offsets[N_NODES] = N_EDGES;
    __syncthreads();

    for (int i = rbeg + t; i < rend; i += 256) {
        int w   = binned[i];
        int pos = atomicAdd(&cur[w >> 17], 1);
        csr_src[pos] = w & 0x1FFFF;
    }
}

// ---------------------------------------------------------------------------
// K5: pull-gather (R10 structure: one node per 32-lane slot, block exits).
// aggb[v] = bf16( hb[v] + sum hb[src] ), fp32 accumulate. No LDS, no stats.
// ---------------------------------------------------------------------------
__global__ __launch_bounds__(256) void gather_kernel(
    const unsigned short* __restrict__ hb,
    const int* __restrict__ offsets,
    const int* __restrict__ csr_src,
    unsigned short* __restrict__ aggb)
{
    int g    = blockIdx.x * 8 + (threadIdx.x >> 5);
    int lane = threadIdx.x & 31;
    if (g >= N_NODES) return;

    const ushort4* X4 = (const ushort4*)hb;
    float4 acc = bf4_to_f4(X4[(size_t)g * 32 + lane]);   // self loop

    int beg = offsets[g];
    int end = offsets[g + 1];

    int e = beg;
    for (; e + 7 < end; e += 8) {
        ushort4 u0 = X4[(size_t)csr_src[e]     * 32 + lane];
        ushort4 u1 = X4[(size_t)csr_src[e + 1] * 32 + lane];
        ushort4 u2 = X4[(size_t)csr_src[e + 2] * 32 + lane];
        ushort4 u3 = X4[(size_t)csr_src[e + 3] * 32 + lane];
        ushort4 u4 = X4[(size_t)csr_src[e + 4] * 32 + lane];
        ushort4 u5 = X4[(size_t)csr_src[e + 5] * 32 + lane];
        ushort4 u6 = X4[(size_t)csr_src[e + 6] * 32 + lane];
        ushort4 u7 = X4[(size_t)csr_src[e + 7] * 32 + lane];
        float4 v0 = bf4_to_f4(u0), v1 = bf4_to_f4(u1);
        float4 v2 = bf4_to_f4(u2), v3 = bf4_to_f4(u3);
        float4 v4 = bf4_to_f4(u4), v5 = bf4_to_f4(u5);
        float4 v6 = bf4_to_f4(u6), v7 = bf4_to_f4(u7);
        acc.x += v0.x + v1.x + v2.x + v3.x + v4.x + v5.x + v6.x + v7.x;
        acc.y += v0.y + v1.y + v2.y + v3.y + v4.y + v5.y + v6.y + v7.y;
        acc.z += v0.z + v1.z + v2.z + v3.z + v4.z + v5.z + v6.z + v7.z;
        acc.w += v0.w + v1.w + v2.w + v3.w + v4.w + v5.w + v6.w + v7.w;
    }
    if (e + 3 < end) {
        ushort4 u0 = X4[(size_t)csr_src[e]     * 32 + lane];
        ushort4 u1 = X4[(size_t)csr_src[e + 1] * 32 + lane];
        ushort4 u2 = X4[(size_t)csr_src[e + 2] * 32 + lane];
        ushort4 u3 = X4[(size_t)csr_src[e + 3] * 32 + lane];
        float4 v0 = bf4_to_f4(u0), v1 = bf4_to_f4(u1);
        float4 v2 = bf4_to_f4(u2), v3 = bf4_to_f4(u3);
        acc.x += v0.x + v1.x + v2.x + v3.x;
        acc.y += v0.y + v1.y + v2.y + v3.y;
        acc.z += v0.z + v1.z + v2.z + v3.z;
        acc.w += v0.w + v1.w + v2.w + v3.w;
        e += 4;
    }
    for (; e < end; ++e) {
        float4 v0 = bf4_to_f4(X4[(size_t)csr_src[e] * 32 + lane]);
        acc.x += v0.x; acc.y += v0.y; acc.z += v0.z; acc.w += v0.w;
    }
    ushort4 o;
    o.x = f2bf(acc.x); o.y = f2bf(acc.y); o.z = f2bf(acc.z); o.w = f2bf(acc.w);
    ((ushort4*)aggb)[(size_t)g * 32 + lane] = o;
}

// ---------------------------------------------------------------------------
// K6: stats partials — 2048 blocks stream aggb (coalesced), LDS-reduce,
// write 256 floats/block to partial[b][0..255]. NO global atomics.
// ---------------------------------------------------------------------------
__global__ __launch_bounds__(256) void stats_partial(
    const unsigned short* __restrict__ aggb,
    float* __restrict__ partial)
{
    const int t    = threadIdx.x;
    const int tc   = t & 31;
    const int trow = t >> 5;
    const int c0   = tc * 4;

    float4 sum = make_float4(0.f, 0.f, 0.f, 0.f);
    float4 ss  = make_float4(0.f, 0.f, 0.f, 0.f);
    for (int r = blockIdx.x * 8 + trow; r < N_NODES; r += SP_BLOCKS * 8) {
        float4 v = bf4_to_f4(((const ushort4*)aggb)[(size_t)r * 32 + tc]);
        sum.x += v.x; sum.y += v.y; sum.z += v.z; sum.w += v.w;
        ss.x  += v.x * v.x; ss.y += v.y * v.y; ss.z += v.z * v.z; ss.w += v.w * v.w;
    }

    __shared__ float red[256 * 8];
    float* my = &red[t * 8];
    my[0] = sum.x; my[1] = sum.y; my[2] = sum.z; my[3] = sum.w;
    my[4] = ss.x;  my[5] = ss.y;  my[6] = ss.z;  my[7] = ss.w;
    __syncthreads();

    if (t < 32) {
        float a8[8];
#pragma unroll
        for (int j = 0; j < 8; j++) a8[j] = red[t * 8 + j];
        for (int gg = 1; gg < 8; gg++)
#pragma unroll
            for (int j = 0; j < 8; j++) a8[j] += red[(gg * 32 + t) * 8 + j];
        float* prow = &partial[(size_t)blockIdx.x * 256];
#pragma unroll
        for (int j = 0; j < 4; j++) {
            prow[t * 4 + j]       = a8[j];
            prow[128 + t * 4 + j] = a8[4 + j];
        }
    }
}

// ---------------------------------------------------------------------------
// K7: stats final — 32 blocks; block j reduces partial rows [j*64, j*64+64).
// Thread t owns column t (coalesced row loads). 32 atomics/address total.
// ---------------------------------------------------------------------------
__global__ __launch_bounds__(256) void stats_final(
    const float* __restrict__ partial,
    float* __restrict__ stats)
{
    const int t = threadIdx.x;
    float s = 0.f;
    const float* base = &partial[(size_t)blockIdx.x * 64 * 256];
    for (int r = 0; r < 64; r++)
        s += base[r * 256 + t];
    unsafeAtomicAdd(&stats[t], s);
}

// ---------------------------------------------------------------------------
// K8: out = relu(gamma*(agg-mean)*rsqrt(var+eps)+beta) + node_feats
// ---------------------------------------------------------------------------
__global__ __launch_bounds__(256) void finalize_kernel(
    const float* __restrict__ stats,
    const float* __restrict__ gamma,
    const float* __restrict__ beta,
    const float* __restrict__ x,
    const unsigned short* __restrict__ aggb,
    float* __restrict__ out)
{
    __shared__ float s_scale[128];
    __shared__ float s_shift[128];
    const int t = threadIdx.x;
    if (t < 128) {
        const float inv_n = 1.0f / (float)N_NODES;
        float mean = stats[t] * inv_n;
        float var  = stats[128 + t] * inv_n - mean * mean;
        float sc   = gamma[t] * rsqrtf(var + BN_EPS);
        s_scale[t] = sc;
        s_shift[t] = beta[t] - mean * sc;
    }
    __syncthreads();

    const long long total = (long long)N_NODES * F / 4;
    long long i0 = (long long)blockIdx.x * blockDim.x + t;
    for (long long i = i0; i < total; i += (long long)gridDim.x * blockDim.x) {
        int cb = (int)(i & 31) * 4;
        float4 v  = bf4_to_f4(((const ushort4*)aggb)[i]);
        float4 xf = ((const float4*)x)[i];
        float4 o;
        o.x = fmaxf(v.x * s_scale[cb + 0] + s_shift[cb + 0], 0.f) + xf.x;
        o.y = fmaxf(v.y * s_scale[cb + 1] + s_shift[cb + 1], 0.f) + xf.y;
        o.z = fmaxf(v.z * s_scale[cb + 2] + s_shift[cb + 2], 0.f) + xf.z;
        o.w = fmaxf(v.w * s_scale[cb + 3] + s_shift[cb + 3], 0.f) + xf.w;
        ((float4*)out)[i] = o;
    }
}

// ---------------------------------------------------------------------------
extern "C" void kernel_launch(void* const* d_in, const int* in_sizes, int n_in,
                              void* d_out, int out_size, void* d_ws, size_t ws_size,
                              hipStream_t stream) {
    const float* node_feats = (const float*)d_in[0];
    const float* W          = (const float*)d_in[1];
    const float* b          = (const float*)d_in[2];
    const float* gamma      = (const float*)d_in[3];
    const float* beta       = (const float*)d_in[4];
    const int*   src        = (const int*)d_in[5];
    const int*   dst        = (const int*)d_in[6];

    float* out     = (float*)d_out;
    char*  ws      = (char*)d_ws;
    float* stats   = (float*)(ws + O_STATS);
    int*   gcur    = (int*)(ws + O_GCUR);
    int*   bbase   = (int*)(ws + O_BBASE);
    int*   offsets = (int*)(ws + O_OFF);
    int*   csr_src = (int*)(ws + O_CSR);
    float* partial = (float*)(ws + O_PART);   // aliases csr_src (dead by then)
    unsigned short* hb   = (unsigned short*)(ws + O_HB);
    unsigned short* aggb = (unsigned short*)(ws + O_AGGB);
    unsigned short* Wb   = (unsigned short*)(ws + O_WB);
    int*   binned  = (int*)(ws + O_BINNED);

    // zero stats (stats_final atomically accumulates into it)
    hipMemsetAsync(d_ws, 0, 1024, stream);

    convert_w<<<64, 256, 0, stream>>>(W, Wb);
    init_cur<<<2, 256, 0, stream>>>(gcur);

    // projection first
    gemm_front<<<(N_NODES + 63) / 64, 256, 0, stream>>>(node_feats, Wb, b, hb);

    // CSR build
    bin_fill<<<FILL_BLOCKS, 256, 0, stream>>>(src, dst, gcur, binned);
    bucket_scan<<<1, 512, 0, stream>>>(gcur, bbase);
    csr_build<<<NB, 256, 0, stream>>>(binned, gcur, bbase, offsets, csr_src);

    // aggregate projected feats (R10 structure: one node per slot)
    gather_kernel<<<(N_NODES + 7) / 8, 256, 0, stream>>>(hb, offsets, csr_src, aggb);

    // atomic-free two-level BN stats
    stats_partial<<<SP_BLOCKS, 256, 0, stream>>>(aggb, partial);
    stats_final<<<32, 256, 0, stream>>>(partial, stats);

    finalize_kernel<<<2048, 256, 0, stream>>>(stats, gamma, beta, node_feats, aggb, out);
}